// Round 5
// baseline (265.451 us; speedup 1.0000x reference)
//
#include <hip/hip_runtime.h>
#include <hip/hip_bf16.h>

// Linear attention via MFMA, fully LDS-free (fragments gathered from global).
// out = S * (qe.KV) / (qe.ksum + 1e-6);  qe/ke = elu(x)+1, masked.
// B=4 H=8 S=8192 D=64. q,k,v,out: float32. masks: int32 (0/1).
// bf16 hi/lo split (3-product) keeps ~fp32 precision (validated absmax 2.4e-4).

#define S_LEN 8192
#define NBH 32
#define KVSTRIDE 4160          // 4096 KV^T [c][d] + 64 ksum (fp32 partials)

typedef __attribute__((ext_vector_type(8))) short short8;
typedef __attribute__((ext_vector_type(4))) float f32x4;

__device__ __forceinline__ float elu1(float x) {
  return x > 0.0f ? (x + 1.0f) : __expf(x);
}
__device__ __forceinline__ unsigned short f2bf(float x) {
  union { __hip_bfloat16 b; unsigned short u; } cv;
  cv.b = __float2bfloat16(x);
  return cv.u;
}
__device__ __forceinline__ float bf2f(unsigned short u) {
  return __uint_as_float(((unsigned)u) << 16);
}
__device__ __forceinline__ void split2(float x, unsigned short& hi, unsigned short& lo) {
  hi = f2bf(x);
  lo = f2bf(x - bf2f(hi));
}

#define MFMA(a,b,c) __builtin_amdgcn_mfma_f32_16x16x32_bf16((a),(b),(c),0,0,0)

// ---------------- Phase 1: partial KV^T + ksum, one wave per s-segment ----------------
// A = ve^T (m=c, k=s), B = ke^T (k=s, n=d)  =>  D[m=c][n=d] = KV^T[c][d].
// Fragment gather: lane holds elem[k = qd4*8+j][tile*16 + mrow] -> dword loads,
// 4x64B coalesced segments per inst. No LDS, no barriers.
__global__ __launch_bounds__(256) void k1_partial(
    const float* __restrict__ kin, const float* __restrict__ vin,
    const int* __restrict__ kv_mask, float* __restrict__ partials,
    int nchunk, int seg_rows) {
  const int tid = threadIdx.x;
  const int lane = tid & 63, w = tid >> 6;
  const int bh = blockIdx.y, b = bh >> 3;       // H=8
  const int seg = blockIdx.x * 4 + w;           // wave-private segment
  const int mrow = lane & 15, qd4 = lane >> 4;

  f32x4 acc[4][4];                              // [tc][td]
#pragma unroll
  for (int i = 0; i < 4; ++i)
#pragma unroll
    for (int j = 0; j < 4; ++j) acc[i][j] = (f32x4){0.f, 0.f, 0.f, 0.f};
  float ks[4] = {0.f, 0.f, 0.f, 0.f};

  const float* kbase = kin + (size_t)bh * S_LEN * 64;
  const float* vbase = vin + (size_t)bh * S_LEN * 64;
  const int s_seg = seg * seg_rows;

  for (int c0 = 0; c0 < seg_rows; c0 += 32) {
    const int s0 = s_seg + c0 + qd4 * 8;        // this lane's first s (j=0)
    float mj[8];
#pragma unroll
    for (int j = 0; j < 8; ++j)
      mj[j] = kv_mask[b * S_LEN + s0 + j] ? 1.0f : 0.0f;

    // B-frags from ke (reused by all 4 tc); ksum accumulated in-flight.
    short8 b_h[4], b_l[4];
#pragma unroll
    for (int td = 0; td < 4; ++td) {
      const float* kp = kbase + (size_t)s0 * 64 + td * 16 + mrow;
      union { unsigned short u[8]; short8 s8; } hh, ll;
#pragma unroll
      for (int j = 0; j < 8; ++j) {
        float ke = elu1(kp[(size_t)j * 64]) * mj[j];
        ks[td] += ke;
        split2(ke, hh.u[j], ll.u[j]);
      }
      b_h[td] = hh.s8; b_l[td] = ll.s8;
    }
    // A-frags from ve, one tc at a time; 12 MFMAs per tc.
#pragma unroll
    for (int tc = 0; tc < 4; ++tc) {
      const float* vp = vbase + (size_t)s0 * 64 + tc * 16 + mrow;
      union { unsigned short u[8]; short8 s8; } hh, ll;
#pragma unroll
      for (int j = 0; j < 8; ++j) {
        float ve = vp[(size_t)j * 64] * (mj[j] * (1.0f / 8192.0f));
        split2(ve, hh.u[j], ll.u[j]);
      }
      short8 a_h = hh.s8, a_l = ll.s8;
#pragma unroll
      for (int td = 0; td < 4; ++td) {
        acc[tc][td] = MFMA(a_h, b_h[td], acc[tc][td]);
        acc[tc][td] = MFMA(a_h, b_l[td], acc[tc][td]);
        acc[tc][td] = MFMA(a_l, b_h[td], acc[tc][td]);
      }
    }
  }
  // ksum: reduce over the 4 qd4 groups (same mrow) -> lanes with qd4==0 hold total.
#pragma unroll
  for (int td = 0; td < 4; ++td) {
    ks[td] += __shfl_xor(ks[td], 32);
    ks[td] += __shfl_xor(ks[td], 16);
  }
  float* p = partials + ((size_t)bh * nchunk + seg) * KVSTRIDE;
  // C/D layout: row = qd4*4+r (c within tile), col = mrow (d within tile).
#pragma unroll
  for (int tc = 0; tc < 4; ++tc)
#pragma unroll
    for (int td = 0; td < 4; ++td)
#pragma unroll
      for (int r = 0; r < 4; ++r)
        p[(tc * 16 + qd4 * 4 + r) * 64 + td * 16 + mrow] = acc[tc][td][r];  // [c][d] coalesced
  if (qd4 == 0) {
#pragma unroll
    for (int td = 0; td < 4; ++td) p[4096 + td * 16 + mrow] = ks[td];
  }
}

// ---------------- Phase 2: reduce partials -> bf16 hi/lo KV^T planes + split ksum ----------------
__global__ __launch_bounds__(256) void k2_reduce(
    const float* __restrict__ partials,
    unsigned short* __restrict__ kvTh, unsigned short* __restrict__ kvTl,
    unsigned short* __restrict__ ksh, unsigned short* __restrict__ ksl, int nchunk) {
  const int idx = blockIdx.x * 256 + threadIdx.x;
  if (idx >= NBH * KVSTRIDE) return;
  const int bh = idx / KVSTRIDE;
  const int e = idx - bh * KVSTRIDE;
  const float* p = partials + (size_t)bh * nchunk * KVSTRIDE + e;
  float s0 = 0.f, s1 = 0.f, s2 = 0.f, s3 = 0.f;
  int c = 0;
  for (; c + 4 <= nchunk; c += 4) {
    s0 += p[(size_t)(c + 0) * KVSTRIDE];
    s1 += p[(size_t)(c + 1) * KVSTRIDE];
    s2 += p[(size_t)(c + 2) * KVSTRIDE];
    s3 += p[(size_t)(c + 3) * KVSTRIDE];
  }
  for (; c < nchunk; ++c) s0 += p[(size_t)c * KVSTRIDE];
  float s = (s0 + s1) + (s2 + s3);
  unsigned short hi, lo;
  split2(s, hi, lo);
  if (e < 4096) {                     // already [c][d]-major; fully coalesced
    kvTh[(size_t)bh * 4096 + e] = hi;
    kvTl[(size_t)bh * 4096 + e] = lo;
  } else {
    ksh[bh * 64 + (e - 4096)] = hi;
    ksl[bh * 64 + (e - 4096)] = lo;
  }
}

// ---------------- Phase 3: out = S * (qe.KV) / (qe.ksum + 1e-6), LDS-free ----------------
// A = qe[l][d] (per-lane contiguous 32B), B = KV^T[c][d] (16B global chunks, L2-hot).
__global__ __launch_bounds__(256) void k3_out(
    const float* __restrict__ qin, const int* __restrict__ q_mask,
    const unsigned short* __restrict__ kvTh, const unsigned short* __restrict__ kvTl,
    const unsigned short* __restrict__ ksh, const unsigned short* __restrict__ ksl,
    float* __restrict__ out) {
  const int tid = threadIdx.x, lane = tid & 63, w = tid >> 6;
  const int rb = blockIdx.x, bh = blockIdx.y, b = bh >> 3;
  const int mrow = lane & 15, qd4 = lane >> 4;
  const int l = rb * 64 + w * 16 + mrow;        // A-operand row this lane loads

  const float m = q_mask[b * S_LEN + l] ? 1.0f : 0.0f;
  f32x4 acc[4];
#pragma unroll
  for (int t = 0; t < 4; ++t) acc[t] = (f32x4){0.f, 0.f, 0.f, 0.f};
  f32x4 accd = (f32x4){0.f, 0.f, 0.f, 0.f};

  const unsigned short* kvh_b = kvTh + (size_t)bh * 4096;
  const unsigned short* kvl_b = kvTl + (size_t)bh * 4096;
#pragma unroll
  for (int k0 = 0; k0 < 64; k0 += 32) {
    const float* qp = qin + ((size_t)bh * S_LEN + l) * 64 + k0 + qd4 * 8;
    float4 q0 = *(const float4*)qp;
    float4 q1 = *(const float4*)(qp + 4);
    float xs[8] = {q0.x, q0.y, q0.z, q0.w, q1.x, q1.y, q1.z, q1.w};
    union { unsigned short u[8]; short8 s8; } ah, al;
#pragma unroll
    for (int j = 0; j < 8; ++j) {
      float qe = elu1(xs[j]) * m;
      split2(qe, ah.u[j], al.u[j]);
    }
    short8 a_h = ah.s8, a_l = al.s8;
    // denominator: broadcast ksum frag (same 16B per quad)
    short8 s_h = *(const short8*)(ksh + bh * 64 + k0 + qd4 * 8);
    short8 s_l = *(const short8*)(ksl + bh * 64 + k0 + qd4 * 8);
    accd = MFMA(a_h, s_h, accd);
    accd = MFMA(a_h, s_l, accd);
    accd = MFMA(a_l, s_h, accd);
#pragma unroll
    for (int t = 0; t < 4; ++t) {
      short8 b_h = *(const short8*)(kvh_b + (size_t)(t * 16 + mrow) * 64 + k0 + qd4 * 8);
      short8 b_l = *(const short8*)(kvl_b + (size_t)(t * 16 + mrow) * 64 + k0 + qd4 * 8);
      acc[t] = MFMA(a_h, b_h, acc[t]);
      acc[t] = MFMA(a_h, b_l, acc[t]);
      acc[t] = MFMA(a_l, b_h, acc[t]);
    }
  }
  // C-layout rows: l_out = rb*64 + w*16 + qd4*4 + r; accd columns all equal den.
  const int row0 = rb * 64 + w * 16 + qd4 * 4;
#pragma unroll
  for (int r = 0; r < 4; ++r) {
    float inv = 8192.0f / (accd[r] + 1e-6f);
#pragma unroll
    for (int t = 0; t < 4; ++t)
      out[((size_t)bh * S_LEN + row0 + r) * 64 + t * 16 + mrow] = acc[t][r] * inv;
  }
}

extern "C" void kernel_launch(void* const* d_in, const int* in_sizes, int n_in,
                              void* d_out, int out_size, void* d_ws, size_t ws_size,
                              hipStream_t stream) {
  const float* q = (const float*)d_in[0];
  const float* k = (const float*)d_in[1];
  const float* v = (const float*)d_in[2];
  const int* qm = (const int*)d_in[3];
  const int* km = (const int*)d_in[4];
  float* out = (float*)d_out;

  int nchunk = 64;                               // 2048 k1 waves (8/CU), 34MB partials
  while (nchunk > 4) {
    size_t need = (size_t)NBH * nchunk * KVSTRIDE * 4
                + (size_t)NBH * 4096 * 2 * 2 + (size_t)NBH * 64 * 2 * 2;
    if (need <= ws_size) break;
    nchunk >>= 1;
  }
  float* partials = (float*)d_ws;                                   // [NBH][nchunk][KVSTRIDE]
  unsigned short* kvTh = (unsigned short*)(partials + (size_t)NBH * nchunk * KVSTRIDE);
  unsigned short* kvTl = kvTh + (size_t)NBH * 4096;
  unsigned short* ksh  = kvTl + (size_t)NBH * 4096;
  unsigned short* ksl  = ksh + NBH * 64;
  int seg_rows = S_LEN / nchunk;

  k1_partial<<<dim3(nchunk / 4, NBH), 256, 0, stream>>>(k, v, km, partials, nchunk, seg_rows);
  int n_elem = NBH * KVSTRIDE;
  k2_reduce<<<dim3((n_elem + 255) / 256), 256, 0, stream>>>(partials, kvTh, kvTl, ksh, ksl, nchunk);
  k3_out<<<dim3(S_LEN / 64, NBH), 256, 0, stream>>>(q, qm, kvTh, kvTl, ksh, ksl, out);
}